// Round 24
// baseline (663.630 us; speedup 1.0000x reference)
//
#include <hip/hip_runtime.h>
#include <stdint.h>

#define CDIM 256
#define NCLS 200
#define NSEL 128
#define SEQ  4096
#define RPB  16      // rows per score-block
#define CCH  32      // einsum chunk (fixed by bitwise semantics)

// ---------------------------------------------------------------------------
// numpy dispatched f32 exp, fused-quadrant rational path (VERIFIED bitwise
// vs harness reference in rounds 19-23 -- do not alter any operation).
// ---------------------------------------------------------------------------
__device__ __forceinline__ float np_expf(float x) {
    const float LOG2E = 1.442695040888963407359924681001892137f;
    const float MAGIC = 12582912.0f;
    const float CW_HI = -6.93145752e-1f;
    const float CW_LO = -1.42860677e-6f;

    float q = __fsub_rn(__fmaf_rn(x, LOG2E, MAGIC), MAGIC);

    float y = __fmaf_rn(q, CW_HI, x);
    y = __fmaf_rn(q, CW_LO, y);

    float num = __fmaf_rn(5.082762527590693718096e-04f, y,
                          6.757896990527504603057e-03f);
    num = __fmaf_rn(num, y, 5.114512081637298353406e-02f);
    num = __fmaf_rn(num, y, 2.473615434895520810817e-01f);
    num = __fmaf_rn(num, y, 7.257664613233124478488e-01f);
    num = __fmaf_rn(num, y, 9.999999999980870924916e-01f);

    float den = __fmaf_rn(2.159509375685829852307e-02f, y,
                          -2.742335390411667452936e-01f);
    den = __fmaf_rn(den, y, 1.0f);

    const float r = __fdiv_rn(num, den);
    return ldexpf(r, (int)q);
}

// ---------------------------------------------------------------------------
// Score kernel: bitwise-identical arithmetic to rounds 19-23 PASS.
// This round: W never touches LDS. Row-group = wave id (xs reads are
// same-address broadcasts); quad = lane (W loads are lane-contiguous 800B
// from L2); explicit 2-deep register prefetch (bufA/bufB) pipelines the
// next i-step's 8 W-row loads under the current step's 128 FMAs.
// K-loop has NO barriers. LDS = xs 16K (reused as lg) + ~1.2K.
// ---------------------------------------------------------------------------
__global__ __launch_bounds__(256) void score_kernel(
    const float* __restrict__ x, const float* __restrict__ W,
    const float* __restrict__ bias, float* __restrict__ scores)
{
    __shared__ __align__(16) float xs[RPB * CDIM];    // 16 KB; lg aliases later
    __shared__ float mx[RPB][16];
    __shared__ float sp[RPB][16];
    __shared__ float mrow[RPB];

    const int tid  = threadIdx.x;
    const int wid  = tid >> 6;
    const int lane = tid & 63;
    const long long row0 = (long long)blockIdx.x * RPB;

    // stage x tile (float4, coalesced; one-time)
    {
        const float4* xg = reinterpret_cast<const float4*>(x + row0 * CDIM);
        float4* xs4 = reinterpret_cast<float4*>(xs);
        for (int i = tid; i < RPB * CDIM / 4; i += 256) xs4[i] = xg[i];
    }
    __syncthreads();

    const int rg = wid;                       // wave-uniform row group (0..3)
    const int q  = (lane < 50) ? lane : 49;   // clamped quad; lanes>=50 discard
    const float* Wq = W + 4 * q;              // + row*NCLS per access

    float acc[4][4][8];                       // [row][class][chain-lane]
    #pragma unroll
    for (int r = 0; r < 4; ++r)
        #pragma unroll
        for (int k = 0; k < 4; ++k)
            #pragma unroll
            for (int j = 0; j < 8; ++j) acc[r][k][j] = 0.0f;

    float4 bufA[8], bufB[8];

    // prefetch chunk 0, i=3 (rows 24..31) into A
    #pragma unroll
    for (int j = 0; j < 8; ++j)
        bufA[j] = *reinterpret_cast<const float4*>(Wq + (24 + j) * NCLS);

    // One pipeline step: issue next loads into NXT, compute with CUR.
    // FMA order per accumulator chain is VERBATIM the verified semantics.
#define STEP(I, CUR, NXT, NROW, DOLOAD)                                       \
    {                                                                         \
        if (DOLOAD) {                                                         \
            _Pragma("unroll")                                                 \
            for (int j = 0; j < 8; ++j)                                       \
                NXT[j] = *reinterpret_cast<const float4*>(                    \
                    Wq + (long long)((NROW) + j) * NCLS);                     \
        }                                                                     \
        float4 xq0[4], xq1[4];                                                \
        _Pragma("unroll")                                                     \
        for (int r = 0; r < 4; ++r) {                                         \
            const float* xrow = &xs[(rg * 4 + r) * CDIM + cc + 8 * (I)];      \
            xq0[r] = *reinterpret_cast<const float4*>(xrow);                  \
            xq1[r] = *reinterpret_cast<const float4*>(xrow + 4);              \
        }                                                                     \
        _Pragma("unroll")                                                     \
        for (int j = 0; j < 8; ++j) {                                         \
            const float4 wv = CUR[j];                                         \
            _Pragma("unroll")                                                 \
            for (int r = 0; r < 4; ++r) {                                     \
                const float xv = (j < 4)                                      \
                    ? reinterpret_cast<const float*>(&xq0[r])[j]              \
                    : reinterpret_cast<const float*>(&xq1[r])[j - 4];         \
                acc[r][0][j] = __fmaf_rn(xv, wv.x, acc[r][0][j]);             \
                acc[r][1][j] = __fmaf_rn(xv, wv.y, acc[r][1][j]);             \
                acc[r][2][j] = __fmaf_rn(xv, wv.z, acc[r][2][j]);             \
                acc[r][3][j] = __fmaf_rn(xv, wv.w, acc[r][3][j]);             \
            }                                                                 \
        }                                                                     \
    }

    for (int c8 = 0; c8 < CDIM / CCH; ++c8) { // 8 chunks, ascending
        const int cc = c8 * CCH;
        STEP(3, bufA, bufB, cc + 16, true)            // compute rows cc+24..31
        STEP(2, bufB, bufA, cc + 8,  true)            // compute rows cc+16..23
        STEP(1, bufA, bufB, cc + 0,  true)            // compute rows cc+8..15
        STEP(0, bufB, bufA, cc + 32 + 24, (c8 < 7))   // compute rows cc+0..7
    }
#undef STEP

    __syncthreads();                  // all waves done reading xs
    float* lg = xs;                   // reuse xs as lg[16][200] (12.8 KB)

    if (lane < 50) {
        const float4 bq = reinterpret_cast<const float4*>(bias)[q];
        const float bv[4] = { bq.x, bq.y, bq.z, bq.w };
        #pragma unroll
        for (int r = 0; r < 4; ++r) {
            float h[4];
            #pragma unroll
            for (int k = 0; k < 4; ++k) {
                const float* a = acc[r][k];
                h[k] = __fadd_rn(
                    __fadd_rn(__fadd_rn(a[0], a[1]), __fadd_rn(a[2], a[3])),
                    __fadd_rn(__fadd_rn(a[4], a[5]), __fadd_rn(a[6], a[7])));
                h[k] = __fadd_rn(h[k], bv[k]);        // b==0: exact no-op
            }
            *reinterpret_cast<float4*>(&lg[(rg * 4 + r) * NCLS + 4 * q]) =
                make_float4(h[0], h[1], h[2], h[3]);
        }
    }
    __syncthreads();

    // ---- row max: 16 rows x 16 slots, fmax tree (bitwise-safe) ----
    {
        const int r = tid >> 4, l = tid & 15;
        float mv = lg[r * NCLS + l];
        for (int n = l + 16; n < NCLS; n += 16) mv = fmaxf(mv, lg[r * NCLS + n]);
        mx[r][l] = mv;
    }
    __syncthreads();
    if (tid < RPB) {
        float mv = mx[tid][0];
        #pragma unroll
        for (int l = 1; l < 16; ++l) mv = fmaxf(mv, mx[tid][l]);
        mrow[tid] = mv;
    }
    __syncthreads();

    // ---- exp: elementwise, parallel ----
    for (int i = tid; i < RPB * NCLS; i += 256) {
        const int r = i / NCLS;
        lg[i] = np_expf(__fsub_rn(lg[i], mrow[r]));
    }
    __syncthreads();

    // ---- pairwise sum: 8 chains x 2 blocks x 16 rows = 256 threads ----
    {
        const int r = tid >> 4, sub = tid & 15;
        const int k = sub & 7, blk = sub >> 3;
        const float* a = &lg[r * NCLS + (blk ? 96 : 0)];
        const int len = blk ? 104 : 96;
        float c = a[k];
        for (int i = 8; i < len; i += 8) c = __fadd_rn(c, a[i + k]);
        sp[r][blk * 8 + k] = c;
    }
    __syncthreads();

    if (tid < RPB) {
        const float* p = sp[tid];
        const float s1 =
            __fadd_rn(__fadd_rn(__fadd_rn(p[0], p[1]), __fadd_rn(p[2], p[3])),
                      __fadd_rn(__fadd_rn(p[4], p[5]), __fadd_rn(p[6], p[7])));
        const float s2 =
            __fadd_rn(__fadd_rn(__fadd_rn(p[8], p[9]), __fadd_rn(p[10], p[11])),
                      __fadd_rn(__fadd_rn(p[12], p[13]), __fadd_rn(p[14], p[15])));
        const float S = __fadd_rn(s1, s2);
        scores[row0 + tid] = __fdiv_rn(1.0f, S);   // emax == 1.0f exactly
    }
}

// ---------------------------------------------------------------------------
// Kernel 2: per batch, sort 4096 packed keys desc (stable, smaller index
// first on ties), gather top-128 rows in rank order. (Unchanged from PASS.)
// ---------------------------------------------------------------------------
__global__ __launch_bounds__(256) void sort_gather_kernel(
    const float* __restrict__ pmax, const float* __restrict__ x,
    float* __restrict__ out)
{
    __shared__ uint64_t K[SEQ];   // 32 KB

    const int tid = threadIdx.x;
    const int b   = blockIdx.x;

    for (int i = tid; i < SEQ; i += 256) {
        const uint32_t pb = __float_as_uint(pmax[(long long)b * SEQ + i]);
        K[i] = ((uint64_t)pb << 12) | (uint64_t)(SEQ - 1 - i);
    }
    __syncthreads();

    for (int k = 2; k <= SEQ; k <<= 1) {
        for (int j = k >> 1; j > 0; j >>= 1) {
            for (int t = tid; t < SEQ / 2; t += 256) {
                const int i = ((t & ~(j - 1)) << 1) | (t & (j - 1));
                const int p = i | j;
                const bool desc = ((i & k) == 0);
                const uint64_t a = K[i], c = K[p];
                const bool sw = desc ? (a < c) : (a > c);
                if (sw) { K[i] = c; K[p] = a; }
            }
            __syncthreads();
        }
    }

    const float4* x4   = reinterpret_cast<const float4*>(x);
    float4*       out4 = reinterpret_cast<float4*>(out);
    for (int t = tid; t < NSEL * (CDIM / 4); t += 256) {
        const int jj = t >> 6;
        const int c4 = t & 63;
        const int idx = (SEQ - 1) - (int)(K[jj] & (uint64_t)(SEQ - 1));
        out4[((long long)b * NSEL + jj) * (CDIM / 4) + c4] =
            x4[((long long)b * SEQ + idx) * (CDIM / 4) + c4];
    }
}

extern "C" void kernel_launch(void* const* d_in, const int* in_sizes, int n_in,
                              void* d_out, int out_size, void* d_ws, size_t ws_size,
                              hipStream_t stream) {
    const float* x    = (const float*)d_in[0];
    const float* W    = (const float*)d_in[1];
    const float* bias = (const float*)d_in[2];
    float* out   = (float*)d_out;
    float* score = (float*)d_ws;                     // 131072 * 4 B = 512 KB

    const long long nrows = (long long)in_sizes[0] / CDIM;   // B*S
    const int B = out_size / (NSEL * CDIM);                  // 32

    score_kernel<<<(int)(nrows / RPB), 256, 0, stream>>>(x, W, bias, score);
    sort_gather_kernel<<<B, 256, 0, stream>>>(score, x, out);
}